// Round 4
// baseline (960.665 us; speedup 1.0000x reference)
//
#include <hip/hip_runtime.h>
#include <hip/hip_bf16.h>
#include <stdint.h>

typedef unsigned short u16;
typedef uint32_t u32;
typedef uint64_t u64;

#define NB 2
#define NA 8732
#define ND 604
#define NC 599
#define NM 300
#define NK 200
#define MT (NC * NM)     // 179700
#define NA4 (NA / 4)     // 2183
#define CONF 0.01f

__device__ __forceinline__ float bf2f(u16 u) { return __uint_as_float(((u32)u) << 16); }

// meta[0] = input storage is true-bf16 (u16 stream); meta[1]/meta[2] = per-batch kept counters.
// Discrimination over the first 8192 u16s:
//  - raw f32: lo-halves have top bit ~50% of the time -> cnt_top >> 0
//  - bf16-rounded-but-f32-stored: even-indexed u16 (lo halves) are all 0x0000
//  - true bf16: values in ~(0x3C23,0x3F80): no top bit, never zero
__global__ void k_detect(const u16* __restrict__ in, u32* __restrict__ meta) {
  __shared__ u32 ws4[4], wz4[4];
  const int tid = threadIdx.x, lane = tid & 63, wid = tid >> 6;
  u32 ct = 0, cz = 0;
  for (int i = tid; i < 8192; i += 256) {
    const u16 v = in[i];
    ct += (u32)(v >> 15);
    cz += (u32)(((i & 1) == 0) && (v == 0));
  }
#pragma unroll
  for (int off = 32; off > 0; off >>= 1) {
    ct += __shfl_down(ct, off, 64);
    cz += __shfl_down(cz, off, 64);
  }
  if (lane == 0) { ws4[wid] = ct; wz4[wid] = cz; }
  __syncthreads();
  if (tid == 0) {
    const u32 tot_top = ws4[0] + ws4[1] + ws4[2] + ws4[3];
    const u32 tot_evz = wz4[0] + wz4[1] + wz4[2] + wz4[3];
    meta[0] = (tot_top == 0 && tot_evz < 1024) ? 1u : 0u;  // else f32 storage
    meta[1] = 0u; meta[2] = 0u; meta[3] = 0u;
  }
}

// per-(b,c): exact stable top-300 (46-bit radix over unique composites) + greedy NMS,
// emitting kept entries as u64 (score32<<32 | (~flat18)<<14 | anchor14).
__global__ __launch_bounds__(256) void k_select_nms(const void* __restrict__ inv,
                                                    u32* __restrict__ meta,
                                                    u64* __restrict__ list) {
  const int bc = blockIdx.x;
  const int b = bc / NC;
  const int c = bc - b * NC;
  const int tid = threadIdx.x;
  const int lane = tid & 63;
  const int wid = tid >> 6;

  __shared__ u32 wsum[4];
  __shared__ u64 cand[512];
  __shared__ u32 sh_cnt;

  const u32 isbf = meta[0];

  // key[e] = f32 bits of score if score > CONF else 0 (NaN -> 0, matching the mask).
  // composite = (key<<14) | (16383 - n): unique per anchor; below-conf entries order by
  // n ascending exactly like the reference's equal NEG entries under stable top_k.
  u32 key[36];
  if (isbf) {
    const u16* basep = (const u16*)inv + (size_t)b * NA * ND + 1 + c;
#pragma unroll
    for (int r = 0; r < 9; ++r) {
      const int i4 = r * 256 + tid;
#pragma unroll
      for (int kk = 0; kk < 4; ++kk) {
        u32 kx = 0;
        if (i4 < NA4) {
          const float f = bf2f(basep[(size_t)(i4 * 4 + kk) * ND]);
          kx = (f > CONF) ? __float_as_uint(f) : 0u;
        }
        key[r * 4 + kk] = kx;
      }
    }
  } else {
    const float* basep = (const float*)inv + (size_t)b * NA * ND + 1 + c;
#pragma unroll
    for (int r = 0; r < 9; ++r) {
      const int i4 = r * 256 + tid;
#pragma unroll
      for (int kk = 0; kk < 4; ++kk) {
        u32 kx = 0;
        if (i4 < NA4) {
          const float f = basep[(size_t)(i4 * 4 + kk) * ND];
          kx = (f > CONF) ? __float_as_uint(f) : 0u;
        }
        key[r * 4 + kk] = kx;
      }
    }
  }

  auto blockSum = [&](u32 v) -> u32 {
#pragma unroll
    for (int off = 32; off > 0; off >>= 1) v += __shfl_down(v, off, 64);
    if (lane == 0) wsum[wid] = v;
    __syncthreads();
    const u32 tot = wsum[0] + wsum[1] + wsum[2] + wsum[3];
    __syncthreads();
    return tot;
  };

  // radix-max search: T = 300th largest composite (unique => count(>=T) == 300 exactly)
  u64 T = 0;
#pragma unroll 1
  for (int bit = 45; bit >= 0; --bit) {
    if (isbf && bit >= 14 && bit < 30) continue;  // true-bf16 scores: low-16 score bits are 0
    const u64 T2 = T | (1ull << bit);
    const u32 Thi = (u32)(T2 >> 14);
    const u32 Tlo = (u32)(T2 & 0x3FFFu);
    u32 cnt = 0;
#pragma unroll
    for (int r = 0; r < 9; ++r) {
#pragma unroll
      for (int kk = 0; kk < 4; ++kk) {
        const u32 k = key[r * 4 + kk];
        const u32 nn = 16383u - (u32)((r * 256 + tid) * 4 + kk);
        cnt += (k > Thi || (k == Thi && nn >= Tlo)) ? 1u : 0u;
      }
    }
    if (blockSum(cnt) >= NM) T = T2;
  }

  // compact exactly 300 into cand[], then bitonic-sort ascending (zeros pad the bottom)
  if (tid == 0) sh_cnt = 0;
  cand[tid] = 0; cand[tid + 256] = 0;
  __syncthreads();
  {
    const u32 Thi = (u32)(T >> 14);
    const u32 Tlo = (u32)(T & 0x3FFFu);
#pragma unroll
    for (int r = 0; r < 9; ++r) {
#pragma unroll
      for (int kk = 0; kk < 4; ++kk) {
        const u32 k = key[r * 4 + kk];
        const u32 nn = 16383u - (u32)((r * 256 + tid) * 4 + kk);
        if (k > Thi || (k == Thi && nn >= Tlo)) {
          const u32 p = atomicAdd(&sh_cnt, 1u);
          if (p < 512) cand[p] = (((u64)k) << 14) | (u64)nn;
        }
      }
    }
  }
  __syncthreads();

#pragma unroll 1
  for (u32 ks = 2; ks <= 512; ks <<= 1) {
#pragma unroll 1
    for (u32 j = ks >> 1; j > 0; j >>= 1) {
#pragma unroll
      for (int rep = 0; rep < 2; ++rep) {
        const u32 i = tid + rep * 256;
        const u32 ixj = i ^ j;
        if (ixj > i) {
          const u64 a = cand[i], bb = cand[ixj];
          const bool up = ((i & ks) == 0);
          if (up ? (a > bb) : (a < bb)) { cand[i] = bb; cand[ixj] = a; }
        }
      }
      __syncthreads();
    }
  }

  // wave 0: greedy NMS over the 300 score-sorted candidates.
  // All IoU-chain arithmetic via _rn intrinsics: prevents FMA contraction of
  // (iar + bar) - ih*iw, which would diverge from the reference's rounded `inter`.
  if (tid < 64) {
    float by0[5], bx0[5], by1[5], bx1[5], bar[5], bv[5];
    u32 bn[5];
    bool sup[5], keep[5];
#pragma unroll
    for (int q = 0; q < 5; ++q) {
      const int j = q * 64 + lane;
      keep[q] = false;
      by0[q] = bx0[q] = by1[q] = bx1[q] = bar[q] = 0.f;
      if (j < NM) {
        const u64 e = cand[511 - j];
        const u32 sb = (u32)(e >> 14);
        const u32 n = 16383u - ((u32)e & 0x3FFFu);
        sup[q] = false;
        bn[q] = n;
        bv[q] = __uint_as_float(sb);   // 0.0f for below-conf candidates
        float cx, cy, w, h;
        if (isbf) {
          const u16* bp = (const u16*)inv + (size_t)(b * NA + n) * ND + 600;
          const ushort4 ub = *(const ushort4*)bp;
          cx = bf2f(ub.x); cy = bf2f(ub.y); w = bf2f(ub.z); h = bf2f(ub.w);
        } else {
          const float* bp = (const float*)inv + (size_t)(b * NA + n) * ND + 600;
          const float4 f4 = *(const float4*)bp;
          cx = f4.x; cy = f4.y; w = f4.z; h = f4.w;
        }
        const float y0 = __fsub_rn(cy, __fmul_rn(h, 0.5f));
        const float x0 = __fsub_rn(cx, __fmul_rn(w, 0.5f));
        const float y1 = __fadd_rn(cy, __fmul_rn(h, 0.5f));
        const float x1 = __fadd_rn(cx, __fmul_rn(w, 0.5f));
        by0[q] = y0; bx0[q] = x0; by1[q] = y1; bx1[q] = x1;
        bar[q] = __fmul_rn(__fsub_rn(y1, y0), __fsub_rn(x1, x0));
      } else {
        bv[q] = 0.f; bn[q] = 0; sup[q] = true;
      }
    }
#pragma unroll
    for (int qi = 0; qi < 5; ++qi) {
      const int lim = (qi == 4) ? (NM - 256) : 64;
#pragma unroll 1
      for (int li = 0; li < lim; ++li) {
        const int kq = (!sup[qi] && bv[qi] > CONF) ? 1 : 0;
        const int ki = __shfl(kq, li, 64);
        if (lane == li) keep[qi] = (ki != 0);
        if (ki) {
          const float iy0 = __shfl(by0[qi], li, 64);
          const float ix0 = __shfl(bx0[qi], li, 64);
          const float iy1 = __shfl(by1[qi], li, 64);
          const float ix1 = __shfl(bx1[qi], li, 64);
          const float iar = __shfl(bar[qi], li, 64);
          const int i = qi * 64 + li;
#pragma unroll
          for (int q = 0; q < 5; ++q) {
            const int j = q * 64 + lane;
            if (j > i && j < NM && !sup[q]) {
              const float ih = fmaxf(__fsub_rn(fminf(iy1, by1[q]), fmaxf(iy0, by0[q])), 0.f);
              const float iw = fmaxf(__fsub_rn(fminf(ix1, bx1[q]), fmaxf(ix0, bx0[q])), 0.f);
              const float inter = __fmul_rn(ih, iw);
              const float uni = __fsub_rn(__fadd_rn(iar, bar[q]), inter);
              if (uni > 0.f && __fdiv_rn(inter, uni) > 0.45f) sup[q] = true;
            }
          }
        }
      }
    }
#pragma unroll
    for (int q = 0; q < 5; ++q) {
      const int j = q * 64 + lane;
      if (j < NM && keep[q]) {
        const u32 p = atomicAdd(&meta[1 + b], 1u);
        const u32 flat = (u32)c * NM + (u32)j;
        if (p < (u32)MT)
          list[(size_t)b * MT + p] = (((u64)__float_as_uint(bv[q])) << 32)
                                   | (((u64)(0x3FFFFu - flat)) << 14)
                                   | (u64)bn[q];
      }
    }
  }
}

// per batch: EXACT top-200 via capless 48-bit radix over rank = entry>>14
// (score32 | ~flat18; unique => count(>=T) == 200 exactly). No candidate cap.
// Output dtype follows the detected input storage (f32 storage -> f32 out).
__global__ __launch_bounds__(1024) void k_topk_out(const void* __restrict__ inv,
                                                   const u32* __restrict__ meta,
                                                   const u64* __restrict__ list,
                                                   void* __restrict__ outv) {
  const int b = blockIdx.x, tid = threadIdx.x, lane = tid & 63, wid = tid >> 6;
  const u32 isbf = meta[0];
  u32 nb = meta[1 + b];
  if (nb > (u32)MT) nb = (u32)MT;
  const u64* lb = list + (size_t)b * MT;

  __shared__ u64 sel[256];
  __shared__ u32 wsum[16];
  __shared__ u32 sh_ss;

  if (tid == 0) sh_ss = 0;
  __syncthreads();

  auto bsum = [&](u32 v) -> u32 {
#pragma unroll
    for (int off = 32; off > 0; off >>= 1) v += __shfl_down(v, off, 64);
    if (lane == 0) wsum[wid] = v;
    __syncthreads();
    u32 t = 0;
#pragma unroll
    for (int wq = 0; wq < 16; ++wq) t += wsum[wq];
    __syncthreads();
    return t;
  };

  u64 T = 0;
  if (nb > (u32)NK) {
#pragma unroll 1
    for (int bit = 47; bit >= 0; --bit) {
      if (isbf && bit >= 18 && bit < 34) continue;  // true-bf16: score low-16 bits are 0
      const u64 T2 = T | (1ull << bit);
      u32 cn = 0;
      for (u32 i = tid; i < nb; i += 1024) cn += ((lb[i] >> 14) >= T2) ? 1u : 0u;
      if (bsum(cn) >= (u32)NK) T = T2;
    }
  }

  for (u32 i = tid; i < nb; i += 1024) {
    if ((lb[i] >> 14) >= T) {
      const u32 p = atomicAdd(&sh_ss, 1u);
      if (p < 256) sel[p] = lb[i];
    }
  }
  __syncthreads();
  u32 tot = sh_ss; if (tot > 256) tot = 256;
  for (u32 p = tot + tid; p < 256; p += 1024) sel[p] = 0;
  __syncthreads();

#pragma unroll 1
  for (u32 ks = 2; ks <= 256; ks <<= 1) {
#pragma unroll 1
    for (u32 j = ks >> 1; j > 0; j >>= 1) {
      if (tid < 256) {
        const u32 i = tid, ixj = i ^ j;
        if (ixj > i) {
          const u64 a = sel[i], c2 = sel[ixj];
          const bool up = ((i & ks) == 0);
          if (up ? (a > c2) : (a < c2)) { sel[i] = c2; sel[ixj] = a; }
        }
      }
      __syncthreads();
    }
  }

  if (tid < NK) {
    const u64 e = sel[255 - tid];   // descending: score desc, then flat asc
    float o0 = 0, o1 = 0, o2 = 0, o3 = 0, o4 = 0, o5 = 0;
    if (e != 0) {
      const u32 sb = (u32)(e >> 32);
      const u32 flat = 0x3FFFFu - ((u32)(e >> 14) & 0x3FFFFu);
      const u32 anchor = (u32)e & 0x3FFFu;
      const u32 cls = flat / NM;
      float cx, cy, w, h;
      if (isbf) {
        const u16* bp = (const u16*)inv + (size_t)(b * NA + anchor) * ND + 600;
        const ushort4 ub = *(const ushort4*)bp;
        cx = bf2f(ub.x); cy = bf2f(ub.y); w = bf2f(ub.z); h = bf2f(ub.w);
      } else {
        const float* bp = (const float*)inv + (size_t)(b * NA + anchor) * ND + 600;
        const float4 f4 = *(const float4*)bp;
        cx = f4.x; cy = f4.y; w = f4.z; h = f4.w;
      }
      const float y0 = __fsub_rn(cy, __fmul_rn(h, 0.5f));
      const float x0 = __fsub_rn(cx, __fmul_rn(w, 0.5f));
      const float y1 = __fadd_rn(cy, __fmul_rn(h, 0.5f));
      const float x1 = __fadd_rn(cx, __fmul_rn(w, 0.5f));
      const float th = __fsub_rn(y1, y0), tw = __fsub_rn(x1, x0);
      o0 = (float)(cls + 1);
      o1 = __uint_as_float(sb);
      o2 = __fadd_rn(x0, __fmul_rn(tw, 0.5f));
      o3 = __fadd_rn(y0, __fmul_rn(th, 0.5f));
      o4 = tw;
      o5 = th;
    }
    if (isbf) {
      __hip_bfloat16* op = (__hip_bfloat16*)outv + ((size_t)b * NK + tid) * 6;
      op[0] = __float2bfloat16(o0); op[1] = __float2bfloat16(o1);
      op[2] = __float2bfloat16(o2); op[3] = __float2bfloat16(o3);
      op[4] = __float2bfloat16(o4); op[5] = __float2bfloat16(o5);
    } else {
      float* op = (float*)outv + ((size_t)b * NK + tid) * 6;
      op[0] = o0; op[1] = o1; op[2] = o2; op[3] = o3; op[4] = o4; op[5] = o5;
    }
  }
}

extern "C" void kernel_launch(void* const* d_in, const int* in_sizes, int n_in,
                              void* d_out, int out_size, void* d_ws, size_t ws_size,
                              hipStream_t stream) {
  (void)in_sizes; (void)n_in; (void)out_size; (void)ws_size;
  const void* in = d_in[0];
  char* ws = (char*)d_ws;

  // workspace: meta u32[8] @0 (32B) | list u64[2*MT] @32 (2,875,200B) => 2,875,232B total
  u32* meta = (u32*)ws;
  u64* list = (u64*)(ws + 32);

  hipLaunchKernelGGL(k_detect, dim3(1), dim3(256), 0, stream, (const u16*)in, meta);
  hipLaunchKernelGGL(k_select_nms, dim3(NB * NC), dim3(256), 0, stream, in, meta, list);
  hipLaunchKernelGGL(k_topk_out, dim3(NB), dim3(1024), 0, stream, in, meta, list, d_out);
}